// Round 18
// baseline (14.858 us; speedup 1.0000x reference)
//
#include <hip/hip_runtime.h>

// Problem constants (match reference)
#define B_ 16
#define N_ 8192
#define U_ 64        // INPUT_DIM
#define W_ 128       // LATENT_DIM
#define BLOCKS_PER_B 32
#define ROWS_PER_BLOCK (N_ / BLOCKS_PER_B)   // 256 = blockDim
#define GRID_ (B_ * BLOCKS_PER_B)            // 512 blocks = exactly 2/CU
#define SENT 0x5AC3F00Du

typedef float f32x4 __attribute__((ext_vector_type(4)));

// Single-node, ZERO-WAIT design (R17 + last-producer-finalizes):
//  * each block publishes its 256-float partial via exchange-RMW (coherence
//    point) + vmcnt(0) ack, then exchange-RMWs its flag.
//  * wave 0 then loads the batch's 32 flags ONCE (no spin) and ballots.
//    The block whose flag-set lands last sees all 32 SENT (its reads are
//    ordered after its own ack >= all siblings' sets) -> >=1 winner
//    guaranteed. Multiple winners are benign: identical deterministic
//    combine (c=0..31 order) -> bit-identical duplicate stores.
//  * winner resets flags (next replay starts clean; replays are
//    stream-ordered so no overlap), combines partials via atomic loads,
//    applies the [64]->[512] map, writes out[b].
// Ledger: R4 grid-sync +107us; R7 threadfence +50us; R8 contended-RMW wait
// +14us; R14/R15 fails = finalizer indexing bug (not coherence).
// ws: [GRID_][256] partials (512 KiB) + GRID_ u32 flags (2 KiB).
// Initial flag state (fresh / 0xAA poison / 0-reset) != SENT in all cases.
// ws slot contract: slot = u*4 + j; j==0 -> S, j=1..3 -> M[j-1].
// out layout: [B,512]: o<128 scalar path, 128+3w+k vector path.

__global__ __launch_bounds__(256, 2) void so3_single_kernel(
    const float* __restrict__ feat,   // [B,N,64]
    const float* __restrict__ pos,    // [B,N,3]
    const float* __restrict__ W0,     // [64,128]
    const float* __restrict__ W1,     // [64,128]
    float* __restrict__ out,          // [B,512]
    float* __restrict__ ws)
{
    const int blk = blockIdx.x;       // 0..511
    const int tid = threadIdx.x;      // 0..255 (4 waves)
    unsigned* flags = (unsigned*)(ws + (size_t)GRID_ * 256);

    const int b     = blk / BLOCKS_PER_B;
    const int chunk = blk % BLOCKS_PER_B;
    const int row0  = chunk * ROWS_PER_BLOCK;
    const int grp   = tid & 15;            // feature group: feats 4*grp..4*grp+3
    const int rsub  = tid >> 4;            // 0..15: row within a 16-row group

    const f32x4* fbase = (const f32x4*)(feat + (size_t)b * N_ * U_);

    // (1) issue all 16 feat loads first -- in flight during the prologue.
    f32x4 fb[16];
    #pragma unroll
    for (int it = 0; it < 16; ++it) {
        const int nl = it * 16 + rsub;
        fb[it] = __builtin_nontemporal_load(
            &fbase[(size_t)(row0 + nl) * 16 + grp]);
    }

    // (2) pos prologue: normalize once per row into LDS.
    __shared__ f32x4 nlds[ROWS_PER_BLOCK]; // 4 KiB
    {
        const float* p = pos + ((size_t)b * N_ + row0 + tid) * 3;
        const float px = p[0], py = p[1], pz = p[2];   // coalesced 3 KiB
        const float inv = rsqrtf(px * px + py * py + pz * pz);
        f32x4 v;
        v.x = px * inv; v.y = py * inv; v.z = pz * inv; v.w = 1.0f;
        nlds[tid] = v;
    }
    __syncthreads();

    // (3) FMA loop. acc[i][k]: i = feat sub-index, k=0..2 -> M[k], k=3 -> S.
    float acc[4][4] = {{0.f,0.f,0.f,0.f},{0.f,0.f,0.f,0.f},
                       {0.f,0.f,0.f,0.f},{0.f,0.f,0.f,0.f}};

    #pragma unroll
    for (int it = 0; it < 16; ++it) {
        const int nl = it * 16 + rsub;
        const f32x4 f  = fb[it];
        const f32x4 nv = nlds[nl];         // ds_read_b128, 16-way broadcast
        #pragma unroll
        for (int k = 0; k < 4; ++k) {
            const float nk = (k == 0) ? nv.x : (k == 1) ? nv.y
                           : (k == 2) ? nv.z : nv.w;   // nv.w==1.0 -> sum
            acc[0][k] = fmaf(f.x, nk, acc[0][k]);
            acc[1][k] = fmaf(f.y, nk, acc[1][k]);
            acc[2][k] = fmaf(f.z, nk, acc[2][k]);
            acc[3][k] = fmaf(f.w, nk, acc[3][k]);
        }
    }

    // (4) block-level combine via LDS (pad 17 breaks stride-16 banks).
    __shared__ float lds[256][17];
    #pragma unroll
    for (int i = 0; i < 4; ++i) {
        lds[tid][i * 4 + 0] = acc[i][0];
        lds[tid][i * 4 + 1] = acc[i][1];
        lds[tid][i * 4 + 2] = acc[i][2];
        lds[tid][i * 4 + 3] = acc[i][3];
    }
    __syncthreads();

    // remap to ws slot contract: tid = (u = tid>>2, j = tid&3);
    // j==0 -> S (lds k=3), j=1..3 -> M[j-1] (lds k=j-1).
    {
        const int u    = tid >> 2;
        const int j    = tid & 3;
        const int ug   = u >> 2;
        const int sub  = u & 3;
        const int slot = (j == 0) ? (sub * 4 + 3) : (sub * 4 + (j - 1));
        float s = 0.f;
        #pragma unroll
        for (int src = 0; src < 16; ++src) {
            const int t = (src & 3) * 64 + (src >> 2) * 16 + ug;
            s += lds[t][slot];
        }

        // (5) publish partial via RMW, ack, then flag via RMW (same wave
        // ordering: partial ack precedes flag issue).
        (void)__hip_atomic_exchange(&ws[(size_t)blk * 256 + tid], s,
                                    __ATOMIC_RELAXED, __HIP_MEMORY_SCOPE_AGENT);
        asm volatile("s_waitcnt vmcnt(0)" ::: "memory");
        __syncthreads();
        if (tid == 0)
            (void)__hip_atomic_exchange(&flags[blk], SENT,
                                        __ATOMIC_RELAXED, __HIP_MEMORY_SCOPE_AGENT);
    }

    // (6) one-shot all-done check (no spin). Wave 0 carries tid 0's flag
    // exchange; vmcnt(0) here orders our set before our reads.
    __shared__ unsigned s_win;
    if (tid < 64) {
        asm volatile("s_waitcnt vmcnt(0)" ::: "memory");
        unsigned ok = 1u;
        if (tid < BLOCKS_PER_B)
            ok = (__hip_atomic_load(&flags[(b << 5) + tid], __ATOMIC_RELAXED,
                                    __HIP_MEMORY_SCOPE_AGENT) == SENT) ? 1u : 0u;
        const unsigned long long mask = __ballot(ok == 1u);
        if (tid == 0) s_win = (mask == ~0ull) ? 1u : 0u;
    }
    __syncthreads();
    if (!s_win) return;

    // ---------------- winner: finalize batch b in place ----------------
    // Reset flags for the next replay (partials independent of flags;
    // duplicate winners reset duplicately -- benign).
    if (tid < BLOCKS_PER_B)
        (void)__hip_atomic_exchange(&flags[(b << 5) + tid], 0u,
                                    __ATOMIC_RELAXED, __HIP_MEMORY_SCOPE_AGENT);

    // Combine 32 chunk partials (atomic loads; fixed c-order -> deterministic,
    // duplicate winners produce bit-identical stores).
    float s2 = 0.f;
    {
        const float* base = ws + (size_t)(b << 5) * 256;
        #pragma unroll
        for (int c = 0; c < BLOCKS_PER_B; ++c)
            s2 += __hip_atomic_load(&base[(size_t)c * 256 + tid],
                                    __ATOMIC_RELAXED, __HIP_MEMORY_SCOPE_AGENT);
    }
    __shared__ float sm[256];
    sm[tid] = s2;                     // sm[u*4 + j]: j==0 S, j=1..3 M[j-1]
    __syncthreads();

    // Tiny matmul per ws slot contract (S at +0, M[k] at +1+k).
    const float scaleS = 0.125f / (float)N_;                       // PATH_COEFF / N
    const float scaleV = 0.125f * 1.7320508075688772f / (float)N_; // PATH_COEFF*sqrt(3)/N

    #pragma unroll
    for (int half = 0; half < 2; ++half) {
        const int o = tid + half * 256;
        float a = 0.f;
        if (o < 128) {
            #pragma unroll
            for (int u = 0; u < 64; ++u) a += sm[u * 4 + 0] * W0[u * 128 + o];
            out[b * 512 + o] = a * scaleS;
        } else {
            const int idx = o - 128;       // 0..383
            const int w = idx / 3;
            const int k = idx - 3 * w;
            #pragma unroll
            for (int u = 0; u < 64; ++u) a += sm[u * 4 + 1 + k] * W1[u * 128 + w];
            out[b * 512 + 128 + idx] = a * scaleV;
        }
    }
}

extern "C" void kernel_launch(void* const* d_in, const int* in_sizes, int n_in,
                              void* d_out, int out_size, void* d_ws, size_t ws_size,
                              hipStream_t stream) {
    const float* feat = (const float*)d_in[0];
    const float* pos  = (const float*)d_in[1];
    const float* W0   = (const float*)d_in[2];
    const float* W1   = (const float*)d_in[3];
    float* out = (float*)d_out;
    float* ws  = (float*)d_ws;   // needs GRID_*256*4 + GRID_*4 = 514 KiB

    so3_single_kernel<<<GRID_, 256, 0, stream>>>(feat, pos, W0, W1, out, ws);
}

// Round 19
// 12.647 us; speedup vs baseline: 1.1748x; 1.1748x over previous
//
#include <hip/hip_runtime.h>

// Problem constants (match reference)
#define B_ 16
#define N_ 8192
#define U_ 64        // INPUT_DIM
#define W_ 128       // LATENT_DIM
#define BLOCKS_PER_B 32
#define ROWS_PER_BLOCK (N_ / BLOCKS_PER_B)   // 256 = blockDim
#define NPROD (B_ * BLOCKS_PER_B)            // 512 producer blocks (2/CU)
#define NFIN  B_                             // 16 finalizer blocks (one per batch)
#define GRID_ (NPROD + NFIN)                 // 528
#define SENT 0x5AC3F00Du

typedef float f32x4 __attribute__((ext_vector_type(4)));

// R17 structure restored (best: 12.55 us). R18's zero-wait variant regressed
// (+2.3 us): unbounded duplicate finalizers in the tail (every late block
// sees all 32 flags SENT -> up to 32x duplicated 32KB combine+matmul).
// Dedicated finalizer blocks bound that work to 16.
// Ledger: R4 grid-sync +107us; R7 threadfence +50us; R8 contended-RMW wait
// +14us; R5 extra memset node +2.3us; R6 fused-atomic epilogue +5.6us;
// R18 zero-wait +2.3us; R14/R15 fails = finalizer indexing bug.
// ws: [NPROD][256] partials (512 KiB) + NPROD u32 flags (2 KiB).
// ws slot contract: slot = u*4 + j; j==0 -> S, j=1..3 -> M[j-1].
// out layout: [B,512]: o<128 scalar path, 128+3w+k vector path.

__global__ __launch_bounds__(256, 2) void so3_single_kernel(
    const float* __restrict__ feat,   // [B,N,64]
    const float* __restrict__ pos,    // [B,N,3]
    const float* __restrict__ W0,     // [64,128]
    const float* __restrict__ W1,     // [64,128]
    float* __restrict__ out,          // [B,512]
    float* __restrict__ ws)
{
    const int blk = blockIdx.x;
    const int tid = threadIdx.x;      // 0..255 (4 waves)
    unsigned* flags = (unsigned*)(ws + (size_t)NPROD * 256);

    if (blk < NPROD) {
        // ---------------- producer ----------------
        const int b     = blk / BLOCKS_PER_B;
        const int chunk = blk % BLOCKS_PER_B;
        const int row0  = chunk * ROWS_PER_BLOCK;
        const int grp   = tid & 15;            // feature group: feats 4*grp..4*grp+3
        const int rsub  = tid >> 4;            // 0..15: row within a 16-row group

        const f32x4* fbase = (const f32x4*)(feat + (size_t)b * N_ * U_);

        // (1) issue all 16 feat loads first -- in flight during the prologue.
        f32x4 fb[16];
        #pragma unroll
        for (int it = 0; it < 16; ++it) {
            const int nl = it * 16 + rsub;
            fb[it] = __builtin_nontemporal_load(
                &fbase[(size_t)(row0 + nl) * 16 + grp]);
        }

        // (2) pos prologue: normalize once per row into LDS.
        __shared__ f32x4 nlds[ROWS_PER_BLOCK]; // 4 KiB
        {
            const float* p = pos + ((size_t)b * N_ + row0 + tid) * 3;
            const float px = p[0], py = p[1], pz = p[2];   // coalesced 3 KiB
            const float inv = rsqrtf(px * px + py * py + pz * pz);
            f32x4 v;
            v.x = px * inv; v.y = py * inv; v.z = pz * inv; v.w = 1.0f;
            nlds[tid] = v;
        }
        __syncthreads();

        // (3) FMA loop. acc[i][k]: i = feat sub-index, k=0..2 -> M[k], k=3 -> S.
        float acc[4][4] = {{0.f,0.f,0.f,0.f},{0.f,0.f,0.f,0.f},
                           {0.f,0.f,0.f,0.f},{0.f,0.f,0.f,0.f}};

        #pragma unroll
        for (int it = 0; it < 16; ++it) {
            const int nl = it * 16 + rsub;
            const f32x4 f  = fb[it];
            const f32x4 nv = nlds[nl];         // ds_read_b128, 16-way broadcast
            #pragma unroll
            for (int k = 0; k < 4; ++k) {
                const float nk = (k == 0) ? nv.x : (k == 1) ? nv.y
                               : (k == 2) ? nv.z : nv.w;   // nv.w==1.0 -> sum
                acc[0][k] = fmaf(f.x, nk, acc[0][k]);
                acc[1][k] = fmaf(f.y, nk, acc[1][k]);
                acc[2][k] = fmaf(f.z, nk, acc[2][k]);
                acc[3][k] = fmaf(f.w, nk, acc[3][k]);
            }
        }

        // (4) block-level combine via LDS (pad 17 breaks stride-16 banks).
        __shared__ float lds[256][17];
        #pragma unroll
        for (int i = 0; i < 4; ++i) {
            lds[tid][i * 4 + 0] = acc[i][0];
            lds[tid][i * 4 + 1] = acc[i][1];
            lds[tid][i * 4 + 2] = acc[i][2];
            lds[tid][i * 4 + 3] = acc[i][3];
        }
        __syncthreads();

        // remap to ws slot contract: tid = (u = tid>>2, j = tid&3);
        // j==0 -> S (lds k=3), j=1..3 -> M[j-1] (lds k=j-1).
        const int u    = tid >> 2;
        const int j    = tid & 3;
        const int ug   = u >> 2;
        const int sub  = u & 3;
        const int slot = (j == 0) ? (sub * 4 + 3) : (sub * 4 + (j - 1));
        float s = 0.f;
        #pragma unroll
        for (int src = 0; src < 16; ++src) {
            const int t = (src & 3) * 64 + (src >> 2) * 16 + ug;
            s += lds[t][slot];
        }

        // (5) publish via RMW (coherence point), ack-wait, flag.
        (void)__hip_atomic_exchange(&ws[(size_t)blk * 256 + tid], s,
                                    __ATOMIC_RELAXED, __HIP_MEMORY_SCOPE_AGENT);
        asm volatile("s_waitcnt vmcnt(0)" ::: "memory");
        __syncthreads();
        if (tid == 0)
            (void)__hip_atomic_exchange(&flags[blk], SENT,
                                        __ATOMIC_RELAXED, __HIP_MEMORY_SCOPE_AGENT);
        return;
    }

    // ---------------- finalizer: one block per batch ----------------
    const int b = blk - NPROD;

    if (tid < BLOCKS_PER_B) {
        while (__hip_atomic_load(&flags[b * BLOCKS_PER_B + tid],
                                 __ATOMIC_RELAXED,
                                 __HIP_MEMORY_SCOPE_AGENT) != SENT)
            __builtin_amdgcn_s_sleep(1);
    }
    __syncthreads();
    // reset flags for the next replay
    if (tid < BLOCKS_PER_B)
        (void)__hip_atomic_exchange(&flags[b * BLOCKS_PER_B + tid], 0u,
                                    __ATOMIC_RELAXED, __HIP_MEMORY_SCOPE_AGENT);

    // cross-chunk combine: slot tid over 32 chunks (atomic loads, coherence
    // point; coalesced 256-float rows per chunk).
    float s = 0.f;
    {
        const float* base = ws + (size_t)b * BLOCKS_PER_B * 256;
        #pragma unroll
        for (int c = 0; c < BLOCKS_PER_B; ++c)
            s += __hip_atomic_load(&base[(size_t)c * 256 + tid],
                                   __ATOMIC_RELAXED, __HIP_MEMORY_SCOPE_AGENT);
    }
    __shared__ float sm[256];
    sm[tid] = s;                      // sm[u*4 + j]: j==0 S, j=1..3 M[j-1]
    __syncthreads();

    // tiny matmul per ws slot contract (S at +0, M[k] at +1+k); sole writer.
    const float scaleS = 0.125f / (float)N_;                       // PATH_COEFF / N
    const float scaleV = 0.125f * 1.7320508075688772f / (float)N_; // PATH_COEFF*sqrt(3)/N

    #pragma unroll
    for (int half = 0; half < 2; ++half) {
        const int o = tid + half * 256;
        float acc = 0.f;
        if (o < 128) {
            #pragma unroll
            for (int u = 0; u < 64; ++u) acc += sm[u * 4 + 0] * W0[u * 128 + o];
            out[b * 512 + o] = acc * scaleS;
        } else {
            const int idx = o - 128;       // 0..383
            const int w = idx / 3;
            const int k = idx - 3 * w;
            #pragma unroll
            for (int u = 0; u < 64; ++u) acc += sm[u * 4 + 1 + k] * W1[u * 128 + w];
            out[b * 512 + 128 + idx] = acc * scaleV;
        }
    }
}

extern "C" void kernel_launch(void* const* d_in, const int* in_sizes, int n_in,
                              void* d_out, int out_size, void* d_ws, size_t ws_size,
                              hipStream_t stream) {
    const float* feat = (const float*)d_in[0];
    const float* pos  = (const float*)d_in[1];
    const float* W0   = (const float*)d_in[2];
    const float* W1   = (const float*)d_in[3];
    float* out = (float*)d_out;
    float* ws  = (float*)d_ws;   // needs NPROD*256*4 + NPROD*4 = 514 KiB

    so3_single_kernel<<<GRID_, 256, 0, stream>>>(feat, pos, W0, W1, out, ws);
}